// Round 17
// baseline (85.230 us; speedup 1.0000x reference)
//
#include <hip/hip_runtime.h>
#include <math.h>
#include <stdint.h>

#define NCLS 128
#define NBANK 8
#define NPASS 3                         // diagnostic: 3 identical passes in ONE dispatch
#define REGION_BYTES 16384              // gLb 8192 | gceb 64 (+pad) | gcntb 4096 | pad
constexpr float ALPHA = 0.5f;
constexpr float BETA_ = 0.5f;
constexpr float EPS_ = 1e-9f;

__global__ void zero_ws(uint32_t* __restrict__ ws) {
    const int t = threadIdx.x;          // 3 regions x 4096 words
    for (int i = t; i < NPASS * (REGION_BYTES / 4); i += 256) ws[i] = 0u;
}

// R15 champion body, executed NPASS times inside one dispatch so the kernel is
// long enough to appear in the rocprof top-5 (the 75us harness poison fills have
// hidden it since R12). Pass 0 writes the real region; passes 1,2 write discard
// regions. Per-wave behavior/contention identical to the champion.
__global__ __launch_bounds__(1024, 4) void loss_main(
    const float* __restrict__ y_pred,
    const int*   __restrict__ y_true,
    double* __restrict__ gLb0, unsigned int* __restrict__ gcntb0,
    double* __restrict__ gceb0, int nrows)
{
    __shared__ float    sL[NCLS];
    __shared__ unsigned scnt[NCLS];
    __shared__ float    sce;

    const int t = threadIdx.x;
    const int lane = t & 63;
    const int half = lane >> 5;
    const int l32  = lane & 31;
    const int wgl  = blockIdx.x * (blockDim.x >> 6) + (t >> 6);   // 0..4095
    const int nW   = gridDim.x * (blockDim.x >> 6);               // 4096
    const int nPairs = nrows >> 1;

    for (int pass = 0; pass < NPASS; ++pass) {
        double*   gLb   = (double*)((char*)gLb0   + pass * REGION_BYTES);
        double*   gceb  = (double*)((char*)gceb0  + pass * REGION_BYTES);
        unsigned* gcntb = (unsigned*)((char*)gcntb0 + pass * REGION_BYTES);

        if (t == 0) sce = 0.f;
        if (t < NCLS) { sL[t] = 0.f; scnt[t] = 0u; }
        __syncthreads();

        float ce_local = 0.f;

        int p0 = wgl * 8;
        for (; p0 + 7 < nPairs; p0 += nW * 8) {
            float4 v[8]; int lab[8];
            const float* base = y_pred + ((size_t)(p0 << 1) + half) * NCLS + (l32 << 2);
            #pragma unroll
            for (int u = 0; u < 8; ++u) {
                v[u]   = *reinterpret_cast<const float4*>(base + (size_t)(u << 1) * NCLS);
                lab[u] = y_true[((p0 + u) << 1) + half];
            }
            float S[8];
            #pragma unroll
            for (int u = 0; u < 8; ++u) {
                const float ex = __expf(v[u].x), ey = __expf(v[u].y);
                const float ez = __expf(v[u].z), ew = __expf(v[u].w);
                S[u] = (ex + ey) + (ez + ew);
            }
            #pragma unroll
            for (int off = 16; off; off >>= 1) {
                #pragma unroll
                for (int u = 0; u < 8; ++u) S[u] += __shfl_xor(S[u], off);
            }
            float tv[8];
            #pragma unroll
            for (int u = 0; u < 8; ++u) {
                const int ls = lab[u] & 3;
                const float vsel = (ls == 0) ? v[u].x : (ls == 1) ? v[u].y
                                 : (ls == 2) ? v[u].z : v[u].w;
                tv[u] = __shfl(vsel, (half << 5) + (lab[u] >> 2));
            }
            if (l32 == 0) {
                #pragma unroll
                for (int u = 0; u < 8; ++u) {
                    ce_local += tv[u] - __logf(S[u]);
                    const float p1 = __expf(v[u].x) / S[u];
                    const float contrib = (lab[u] == 0) ? ALPHA * __logf(p1 + EPS_)
                                                        : __logf(1.f - p1 + EPS_);
                    atomicAdd(&sL[lab[u]], contrib);
                    atomicAdd(&scnt[lab[u]], 1u);
                }
            }
        }
        for (; p0 < nPairs; ++p0) {
            const int row = (p0 << 1) + half;
            const float4 v = *reinterpret_cast<const float4*>(
                y_pred + (size_t)row * NCLS + (l32 << 2));
            const int lab = y_true[row];
            const float ex = __expf(v.x), ey = __expf(v.y);
            const float ez = __expf(v.z), ew = __expf(v.w);
            float S = (ex + ey) + (ez + ew);
            #pragma unroll
            for (int off = 16; off; off >>= 1) S += __shfl_xor(S, off);
            const int ls = lab & 3;
            const float vsel = (ls == 0) ? v.x : (ls == 1) ? v.y : (ls == 2) ? v.z : v.w;
            const float tv = __shfl(vsel, (half << 5) + (lab >> 2));
            if (l32 == 0) {
                ce_local += tv - __logf(S);
                const float p1 = ex / S;
                const float contrib = (lab == 0) ? ALPHA * __logf(p1 + EPS_)
                                                 : __logf(1.f - p1 + EPS_);
                atomicAdd(&sL[lab], contrib);
                atomicAdd(&scnt[lab], 1u);
            }
        }
        if ((nrows & 1) && wgl == 0) {
            const int row = nrows - 1;
            const float4 v = *reinterpret_cast<const float4*>(
                y_pred + (size_t)row * NCLS + (l32 << 2));
            const int lab = y_true[row];
            const float ex = __expf(v.x), ey = __expf(v.y);
            const float ez = __expf(v.z), ew = __expf(v.w);
            float S = (ex + ey) + (ez + ew);
            #pragma unroll
            for (int off = 16; off; off >>= 1) S += __shfl_xor(S, off);
            const int ls = lab & 3;
            const float vsel = (ls == 0) ? v.x : (ls == 1) ? v.y : (ls == 2) ? v.z : v.w;
            const float tv = __shfl(vsel, (half << 5) + (lab >> 2));
            if (lane == 0) {
                ce_local += tv - __logf(S);
                const float p1 = ex / S;
                const float contrib = (lab == 0) ? ALPHA * __logf(p1 + EPS_)
                                                 : __logf(1.f - p1 + EPS_);
                atomicAdd(&sL[lab], contrib);
                atomicAdd(&scnt[lab], 1u);
            }
        }

        float lp = ce_local;
        #pragma unroll
        for (int off = 32; off; off >>= 1) lp += __shfl_xor(lp, off);
        if (lane == 0) atomicAdd(&sce, lp);
        __syncthreads();

        const int bank = blockIdx.x & (NBANK - 1);
        if (t < NCLS) {
            const int c = (t + blockIdx.x) & (NCLS - 1);
            if (scnt[c]) {
                atomicAdd(&gLb[c * NBANK + bank], (double)sL[c]);
                atomicAdd(&gcntb[c * NBANK + bank], scnt[c]);
            }
        }
        if (t == 0) atomicAdd(&gceb[bank], (double)sce);
        __syncthreads();   // flush reads sL done before next pass re-inits
    }
}

__global__ void loss_final(const double* __restrict__ gLb,
                           const unsigned int* __restrict__ gcntb,
                           const double* __restrict__ gceb,
                           float* __restrict__ out, int nrows)
{
    const int lane = threadIdx.x;   // 64 threads
    double cnt0 = 0.0;
    #pragma unroll
    for (int b = 0; b < NBANK; ++b) cnt0 += (double)gcntb[0 * NBANK + b];
    const double denom = (double)nrows - cnt0;

    double local = 0.0;
    for (int c = lane; c < NCLS; c += 64) {
        double Lc = 0.0, nc = 0.0;
        #pragma unroll
        for (int b = 0; b < NBANK; ++b) {
            Lc += gLb[c * NBANK + b];
            nc += (double)gcntb[c * NBANK + b];
        }
        if (c == 0) local += Lc;                          // ALPHA pre-applied
        else        local += (double)BETA_ * (1.0 - nc / denom) * Lc;
    }
    #pragma unroll
    for (int off = 32; off; off >>= 1) local += __shfl_down(local, off);
    if (lane == 0) {
        double ce = 0.0;
        #pragma unroll
        for (int b = 0; b < NBANK; ++b) ce += gceb[b];
        ce = -ce / (double)nrows;
        out[0] = (float)(ce - local / (double)nrows);
    }
}

extern "C" void kernel_launch(void* const* d_in, const int* in_sizes, int n_in,
                              void* d_out, int out_size, void* d_ws, size_t ws_size,
                              hipStream_t stream) {
    const float* y_pred = (const float*)d_in[0];
    const int*   y_true = (const int*)d_in[1];
    const int nrows = in_sizes[1];

    double*   gLb   = (double*)d_ws;                       // region 0: 8192 B
    double*   gceb  = (double*)((char*)d_ws + 8192);       // 64 B
    unsigned* gcntb = (unsigned*)((char*)d_ws + 8256);     // 4096 B

    zero_ws<<<dim3(1), dim3(256), 0, stream>>>((uint32_t*)d_ws);

    loss_main<<<dim3(256), dim3(1024), 0, stream>>>(y_pred, y_true, gLb, gcntb, gceb, nrows);
    loss_final<<<dim3(1), dim3(64), 0, stream>>>(gLb, gcntb, gceb, (float*)d_out, nrows);
}

// Round 18
// 44.941 us; speedup vs baseline: 1.8965x; 1.8965x over previous
//
#include <hip/hip_runtime.h>
#include <math.h>
#include <stdint.h>

#define NCLS 128
#define NBANK 8
constexpr float ALPHA = 0.5f;
constexpr float BETA_ = 0.5f;
constexpr float EPS_ = 1e-9f;

// ws: gLb[128][8] double (8192 B) | gceb[8] double (64 B) | gcntb[128][8] uint (4096 B)
__global__ void zero_ws(uint32_t* __restrict__ ws) {
    const int t = threadIdx.x;               // 3088 words
    for (int i = t; i < 3088; i += 256) ws[i] = 0u;
}

// R15 champion + (a) 512 blocks -> 2 blocks/CU, 32 waves/CU (grid was the
// occupancy cap: VGPR 52 <= 64 so 2 blocks fit); (b) leaner epilogue: e0 kept
// from EXP phase and contrib via log identity (no div, no exp recompute):
//   label==0: ALPHA*(log(e0+eps*S)-logS) == ALPHA*log(p1+eps)
//   else:            log(S-e0+eps*S)-logS == log(1-p1+eps)      (exact algebra)
__global__ __launch_bounds__(1024, 4) void loss_main(
    const float* __restrict__ y_pred,
    const int*   __restrict__ y_true,
    double* __restrict__ gLb, unsigned int* __restrict__ gcntb,
    double* __restrict__ gceb, int nrows)
{
    __shared__ float    sL[NCLS];
    __shared__ unsigned scnt[NCLS];
    __shared__ float    sce;

    const int t = threadIdx.x;
    if (t == 0) sce = 0.f;
    if (t < NCLS) { sL[t] = 0.f; scnt[t] = 0u; }
    __syncthreads();

    const int lane = t & 63;
    const int half = lane >> 5;
    const int l32  = lane & 31;
    const int wgl  = blockIdx.x * (blockDim.x >> 6) + (t >> 6);   // 0..8191
    const int nW   = gridDim.x * (blockDim.x >> 6);               // 8192
    const int nPairs = nrows >> 1;

    float ce_local = 0.f;

    int p0 = wgl * 8;
    for (; p0 + 7 < nPairs; p0 += nW * 8) {
        float4 v[8]; int lab[8];
        const float* base = y_pred + ((size_t)(p0 << 1) + half) * NCLS + (l32 << 2);
        #pragma unroll
        for (int u = 0; u < 8; ++u) {
            v[u]   = *reinterpret_cast<const float4*>(base + (size_t)(u << 1) * NCLS);
            lab[u] = y_true[((p0 + u) << 1) + half];
        }
        float S[8], e0[8];
        #pragma unroll
        for (int u = 0; u < 8; ++u) {
            const float ex = __expf(v[u].x), ey = __expf(v[u].y);
            const float ez = __expf(v[u].z), ew = __expf(v[u].w);
            e0[u] = ex;
            S[u]  = (ex + ey) + (ez + ew);
        }
        #pragma unroll
        for (int off = 16; off; off >>= 1) {
            #pragma unroll
            for (int u = 0; u < 8; ++u) S[u] += __shfl_xor(S[u], off);
        }
        float tv[8];
        #pragma unroll
        for (int u = 0; u < 8; ++u) {
            const int ls = lab[u] & 3;
            const float vsel = (ls == 0) ? v[u].x : (ls == 1) ? v[u].y
                             : (ls == 2) ? v[u].z : v[u].w;
            tv[u] = __shfl(vsel, (half << 5) + (lab[u] >> 2));
        }
        if (l32 == 0) {
            #pragma unroll
            for (int u = 0; u < 8; ++u) {
                const float logS = __logf(S[u]);
                ce_local += tv[u] - logS;
                const float d = (lab[u] == 0) ? e0[u] : (S[u] - e0[u]);
                const float c0 = __logf(__fmaf_rn(EPS_, S[u], d)) - logS;
                const float contrib = (lab[u] == 0) ? ALPHA * c0 : c0;
                atomicAdd(&sL[lab[u]], contrib);
                atomicAdd(&scnt[lab[u]], 1u);
            }
        }
    }
    // tail: leftover single pairs (empty when 8*nW | nPairs, true at 262144 rows)
    for (; p0 < nPairs; ++p0) {
        const int row = (p0 << 1) + half;
        const float4 v = *reinterpret_cast<const float4*>(
            y_pred + (size_t)row * NCLS + (l32 << 2));
        const int lab = y_true[row];
        const float ex = __expf(v.x), ey = __expf(v.y);
        const float ez = __expf(v.z), ew = __expf(v.w);
        float S = (ex + ey) + (ez + ew);
        #pragma unroll
        for (int off = 16; off; off >>= 1) S += __shfl_xor(S, off);
        const int ls = lab & 3;
        const float vsel = (ls == 0) ? v.x : (ls == 1) ? v.y : (ls == 2) ? v.z : v.w;
        const float tv = __shfl(vsel, (half << 5) + (lab >> 2));
        if (l32 == 0) {
            const float logS = __logf(S);
            ce_local += tv - logS;
            const float d = (lab == 0) ? ex : (S - ex);
            const float c0 = __logf(__fmaf_rn(EPS_, S, d)) - logS;
            const float contrib = (lab == 0) ? ALPHA * c0 : c0;
            atomicAdd(&sL[lab], contrib);
            atomicAdd(&scnt[lab], 1u);
        }
    }
    if ((nrows & 1) && wgl == 0) {
        const int row = nrows - 1;
        const float4 v = *reinterpret_cast<const float4*>(
            y_pred + (size_t)row * NCLS + (l32 << 2));
        const int lab = y_true[row];
        if (half == 0) {
            const float ex = __expf(v.x), ey = __expf(v.y);
            const float ez = __expf(v.z), ew = __expf(v.w);
            float S = (ex + ey) + (ez + ew);
            #pragma unroll
            for (int off = 16; off; off >>= 1) S += __shfl_xor(S, off);
            const int ls = lab & 3;
            const float vsel = (ls == 0) ? v.x : (ls == 1) ? v.y : (ls == 2) ? v.z : v.w;
            const float tv = __shfl(vsel, (half << 5) + (lab >> 2));
            if (l32 == 0) {
                const float logS = __logf(S);
                ce_local += tv - logS;
                const float d = (lab == 0) ? ex : (S - ex);
                const float c0 = __logf(__fmaf_rn(EPS_, S, d)) - logS;
                const float contrib = (lab == 0) ? ALPHA * c0 : c0;
                atomicAdd(&sL[lab], contrib);
                atomicAdd(&scnt[lab], 1u);
            }
        }
    }

    float lp = ce_local;
    #pragma unroll
    for (int off = 32; off; off >>= 1) lp += __shfl_xor(lp, off);
    if (lane == 0) atomicAdd(&sce, lp);
    __syncthreads();

    // banked flush: 512 blocks / 8 banks -> 64-deep chains on 1024 addresses
    const int bank = blockIdx.x & (NBANK - 1);
    if (t < NCLS) {
        const int c = (t + blockIdx.x) & (NCLS - 1);
        if (scnt[c]) {
            atomicAdd(&gLb[c * NBANK + bank], (double)sL[c]);
            atomicAdd(&gcntb[c * NBANK + bank], scnt[c]);
        }
    }
    if (t == 0) atomicAdd(&gceb[bank], (double)sce);
}

__global__ void loss_final(const double* __restrict__ gLb,
                           const unsigned int* __restrict__ gcntb,
                           const double* __restrict__ gceb,
                           float* __restrict__ out, int nrows)
{
    const int lane = threadIdx.x;   // 64 threads
    double cnt0 = 0.0;
    #pragma unroll
    for (int b = 0; b < NBANK; ++b) cnt0 += (double)gcntb[0 * NBANK + b];
    const double denom = (double)nrows - cnt0;

    double local = 0.0;
    for (int c = lane; c < NCLS; c += 64) {
        double Lc = 0.0, nc = 0.0;
        #pragma unroll
        for (int b = 0; b < NBANK; ++b) {
            Lc += gLb[c * NBANK + b];
            nc += (double)gcntb[c * NBANK + b];
        }
        if (c == 0) local += Lc;                          // ALPHA pre-applied
        else        local += (double)BETA_ * (1.0 - nc / denom) * Lc;
    }
    #pragma unroll
    for (int off = 32; off; off >>= 1) local += __shfl_down(local, off);
    if (lane == 0) {
        double ce = 0.0;
        #pragma unroll
        for (int b = 0; b < NBANK; ++b) ce += gceb[b];
        ce = -ce / (double)nrows;
        out[0] = (float)(ce - local / (double)nrows);
    }
}

extern "C" void kernel_launch(void* const* d_in, const int* in_sizes, int n_in,
                              void* d_out, int out_size, void* d_ws, size_t ws_size,
                              hipStream_t stream) {
    const float* y_pred = (const float*)d_in[0];
    const int*   y_true = (const int*)d_in[1];
    const int nrows = in_sizes[1];

    double*   gLb   = (double*)d_ws;                       // 8192 B
    double*   gceb  = (double*)((char*)d_ws + 8192);       // 64 B
    unsigned* gcntb = (unsigned*)((char*)d_ws + 8256);     // 4096 B

    zero_ws<<<dim3(1), dim3(256), 0, stream>>>((uint32_t*)d_ws);

    loss_main<<<dim3(512), dim3(1024), 0, stream>>>(y_pred, y_true, gLb, gcntb, gceb, nrows);
    loss_final<<<dim3(1), dim3(64), 0, stream>>>(gLb, gcntb, gceb, (float*)d_out, nrows);
}

// Round 19
// 40.046 us; speedup vs baseline: 2.1283x; 1.1222x over previous
//
#include <hip/hip_runtime.h>
#include <math.h>
#include <stdint.h>

#define NCLS 128
#define NBANK 8
constexpr float ALPHA = 0.5f;
constexpr float BETA_ = 0.5f;
constexpr float EPS_ = 1e-9f;

// ws: gLb[128][8] double (8192 B) | gceb[8] double (64 B) | gcntb[128][8] uint (4096 B)
__global__ void zero_ws(uint32_t* __restrict__ ws) {
    const int t = threadIdx.x;               // 3088 words
    for (int i = t; i < 3088; i += 256) ws[i] = 0u;
}

// R15 champion (256x1024, banked flush) + instruction-stream fixes:
//  (1) sched_barrier(0) after the 16-load phase: compiler cannot sink loads into
//      the compute (R17's VGPR=52 proved it was re-serializing the batch; the
//      R14 probe with live batches hit 6.8 TB/s).
//  (2) no tv broadcast: label-owner lane adds its own vsel to ce_local; lane 0
//      adds -logS. Same sum, -8 DS ops and -8 regs per batch.
//  (3) R18 epilogue algebra (exact): contrib = log(d + eps*S) - logS,
//      d = e0 (label==0, *ALPHA) or S-e0; no divide, no exp recompute.
__global__ __launch_bounds__(1024, 4) void loss_main(
    const float* __restrict__ y_pred,
    const int*   __restrict__ y_true,
    double* __restrict__ gLb, unsigned int* __restrict__ gcntb,
    double* __restrict__ gceb, int nrows)
{
    __shared__ float    sL[NCLS];
    __shared__ unsigned scnt[NCLS];
    __shared__ float    sce;

    const int t = threadIdx.x;
    if (t == 0) sce = 0.f;
    if (t < NCLS) { sL[t] = 0.f; scnt[t] = 0u; }
    __syncthreads();

    const int lane = t & 63;
    const int half = lane >> 5;
    const int l32  = lane & 31;
    const int wgl  = blockIdx.x * (blockDim.x >> 6) + (t >> 6);   // 0..4095
    const int nW   = gridDim.x * (blockDim.x >> 6);               // 4096
    const int nPairs = nrows >> 1;

    float ce_local = 0.f;

    int p0 = wgl * 8;
    for (; p0 + 7 < nPairs; p0 += nW * 8) {
        // ---- LOAD phase: 8x float4 (1KB/wave each) + 8 labels, all issued first
        float4 v[8]; int lab[8];
        const float* base = y_pred + ((size_t)(p0 << 1) + half) * NCLS + (l32 << 2);
        #pragma unroll
        for (int u = 0; u < 8; ++u) {
            v[u]   = *reinterpret_cast<const float4*>(base + (size_t)(u << 1) * NCLS);
            lab[u] = y_true[((p0 + u) << 1) + half];
        }
        __builtin_amdgcn_sched_barrier(0);   // pin: no compute issued before loads

        // ---- EXP phase: v dies here (S4, e0, owner-vsel extracted)
        float S[8], e0[8];
        #pragma unroll
        for (int u = 0; u < 8; ++u) {
            const float ex = __expf(v[u].x), ey = __expf(v[u].y);
            const float ez = __expf(v[u].z), ew = __expf(v[u].w);
            e0[u] = ex;
            S[u]  = (ex + ey) + (ez + ew);
            if ((lab[u] >> 2) == l32) {      // owner lane folds target logit now
                const int ls = lab[u] & 3;
                ce_local += (ls == 0) ? v[u].x : (ls == 1) ? v[u].y
                          : (ls == 2) ? v[u].z : v[u].w;
            }
        }
        // ---- 8 interleaved 5-step butterflies (S lands on all lanes)
        #pragma unroll
        for (int off = 16; off; off >>= 1) {
            #pragma unroll
            for (int u = 0; u < 8; ++u) S[u] += __shfl_xor(S[u], off);
        }
        // ---- masked epilogue (lanes l32==0): logS + class contribution
        if (l32 == 0) {
            #pragma unroll
            for (int u = 0; u < 8; ++u) {
                const float logS = __logf(S[u]);
                ce_local -= logS;
                const float d = (lab[u] == 0) ? e0[u] : (S[u] - e0[u]);
                const float c0 = __logf(__fmaf_rn(EPS_, S[u], d)) - logS;
                const float contrib = (lab[u] == 0) ? ALPHA * c0 : c0;
                atomicAdd(&sL[lab[u]], contrib);
                atomicAdd(&scnt[lab[u]], 1u);
            }
        }
    }
    // tail: leftover single pairs (empty at 262144 rows; kept for generality)
    for (; p0 < nPairs; ++p0) {
        const int row = (p0 << 1) + half;
        const float4 v = *reinterpret_cast<const float4*>(
            y_pred + (size_t)row * NCLS + (l32 << 2));
        const int lab = y_true[row];
        const float ex = __expf(v.x), ey = __expf(v.y);
        const float ez = __expf(v.z), ew = __expf(v.w);
        float S = (ex + ey) + (ez + ew);
        if ((lab >> 2) == l32) {
            const int ls = lab & 3;
            ce_local += (ls == 0) ? v.x : (ls == 1) ? v.y : (ls == 2) ? v.z : v.w;
        }
        #pragma unroll
        for (int off = 16; off; off >>= 1) S += __shfl_xor(S, off);
        if (l32 == 0) {
            const float logS = __logf(S);
            ce_local -= logS;
            const float d = (lab == 0) ? ex : (S - ex);
            const float c0 = __logf(__fmaf_rn(EPS_, S, d)) - logS;
            const float contrib = (lab == 0) ? ALPHA * c0 : c0;
            atomicAdd(&sL[lab], contrib);
            atomicAdd(&scnt[lab], 1u);
        }
    }
    if ((nrows & 1) && wgl == 0) {
        const int row = nrows - 1;
        const float4 v = *reinterpret_cast<const float4*>(
            y_pred + (size_t)row * NCLS + (l32 << 2));
        const int lab = y_true[row];
        if (half == 0) {
            const float ex = __expf(v.x), ey = __expf(v.y);
            const float ez = __expf(v.z), ew = __expf(v.w);
            float S = (ex + ey) + (ez + ew);
            if ((lab >> 2) == l32) {
                const int ls = lab & 3;
                ce_local += (ls == 0) ? v.x : (ls == 1) ? v.y : (ls == 2) ? v.z : v.w;
            }
            #pragma unroll
            for (int off = 16; off; off >>= 1) S += __shfl_xor(S, off);
            if (l32 == 0) {
                const float logS = __logf(S);
                ce_local -= logS;
                const float d = (lab == 0) ? ex : (S - ex);
                const float c0 = __logf(__fmaf_rn(EPS_, S, d)) - logS;
                const float contrib = (lab == 0) ? ALPHA * c0 : c0;
                atomicAdd(&sL[lab], contrib);
                atomicAdd(&scnt[lab], 1u);
            }
        }
    }

    float lp = ce_local;
    #pragma unroll
    for (int off = 32; off; off >>= 1) lp += __shfl_xor(lp, off);
    if (lane == 0) atomicAdd(&sce, lp);
    __syncthreads();

    // banked flush: 256 blocks / 8 banks -> 32-deep chains on 1024 addresses
    const int bank = blockIdx.x & (NBANK - 1);
    if (t < NCLS) {
        const int c = (t + blockIdx.x) & (NCLS - 1);
        if (scnt[c]) {
            atomicAdd(&gLb[c * NBANK + bank], (double)sL[c]);
            atomicAdd(&gcntb[c * NBANK + bank], scnt[c]);
        }
    }
    if (t == 0) atomicAdd(&gceb[bank], (double)sce);
}

__global__ void loss_final(const double* __restrict__ gLb,
                           const unsigned int* __restrict__ gcntb,
                           const double* __restrict__ gceb,
                           float* __restrict__ out, int nrows)
{
    const int lane = threadIdx.x;   // 64 threads
    double cnt0 = 0.0;
    #pragma unroll
    for (int b = 0; b < NBANK; ++b) cnt0 += (double)gcntb[0 * NBANK + b];
    const double denom = (double)nrows - cnt0;

    double local = 0.0;
    for (int c = lane; c < NCLS; c += 64) {
        double Lc = 0.0, nc = 0.0;
        #pragma unroll
        for (int b = 0; b < NBANK; ++b) {
            Lc += gLb[c * NBANK + b];
            nc += (double)gcntb[c * NBANK + b];
        }
        if (c == 0) local += Lc;                          // ALPHA pre-applied
        else        local += (double)BETA_ * (1.0 - nc / denom) * Lc;
    }
    #pragma unroll
    for (int off = 32; off; off >>= 1) local += __shfl_down(local, off);
    if (lane == 0) {
        double ce = 0.0;
        #pragma unroll
        for (int b = 0; b < NBANK; ++b) ce += gceb[b];
        ce = -ce / (double)nrows;
        out[0] = (float)(ce - local / (double)nrows);
    }
}

extern "C" void kernel_launch(void* const* d_in, const int* in_sizes, int n_in,
                              void* d_out, int out_size, void* d_ws, size_t ws_size,
                              hipStream_t stream) {
    const float* y_pred = (const float*)d_in[0];
    const int*   y_true = (const int*)d_in[1];
    const int nrows = in_sizes[1];

    double*   gLb   = (double*)d_ws;                       // 8192 B
    double*   gceb  = (double*)((char*)d_ws + 8192);       // 64 B
    unsigned* gcntb = (unsigned*)((char*)d_ws + 8256);     // 4096 B

    zero_ws<<<dim3(1), dim3(256), 0, stream>>>((uint32_t*)d_ws);

    loss_main<<<dim3(256), dim3(1024), 0, stream>>>(y_pred, y_true, gLb, gcntb, gceb, nrows);
    loss_final<<<dim3(1), dim3(64), 0, stream>>>(gLb, gcntb, gceb, (float*)d_out, nrows);
}

// Round 22
// 38.332 us; speedup vs baseline: 2.2235x; 1.0447x over previous
//
#include <hip/hip_runtime.h>
#include <math.h>
#include <stdint.h>

#define NCLS 128
#define NBANK 8
constexpr float ALPHA = 0.5f;
constexpr float BETA_ = 0.5f;
constexpr float EPS_ = 1e-9f;

// ws: gLb[128][8] double (8192 B) | gceb[8] double (64 B) | gcntb[128][8] uint (4096 B)
__global__ void zero_ws(uint32_t* __restrict__ ws) {
    const int t = threadIdx.x;               // 3088 words
    for (int i = t; i < 3088; i += 256) ws[i] = 0u;
}

// R19 champion + WAVE-PARALLEL EPILOGUE: after the butterfly S[u] is on all
// lanes; e0[u] is broadcast from lane 0/32 (8 shuffles) and lane l32==u takes
// ownership of row-pair u. The per-batch epilogue (16 logs + 16 LDS atomics,
// previously serialized on 2-of-64 lanes) now runs on 16 lanes in parallel:
// ~2 log wave-ops + ~2 atomic slots instead of 16+16 (common-mistake #6).
__global__ __launch_bounds__(1024, 4) void loss_main(
    const float* __restrict__ y_pred,
    const int*   __restrict__ y_true,
    double* __restrict__ gLb, unsigned int* __restrict__ gcntb,
    double* __restrict__ gceb, int nrows)
{
    __shared__ float    sL[NCLS];
    __shared__ unsigned scnt[NCLS];
    __shared__ float    sce;

    const int t = threadIdx.x;
    if (t == 0) sce = 0.f;
    if (t < NCLS) { sL[t] = 0.f; scnt[t] = 0u; }
    __syncthreads();

    const int lane = t & 63;
    const int half = lane >> 5;
    const int l32  = lane & 31;
    const int wgl  = blockIdx.x * (blockDim.x >> 6) + (t >> 6);   // 0..4095
    const int nW   = gridDim.x * (blockDim.x >> 6);               // 4096
    const int nPairs = nrows >> 1;

    float ce_local = 0.f;

    int p0 = wgl * 8;
    for (; p0 + 7 < nPairs; p0 += nW * 8) {
        // ---- LOAD phase: 8x float4 (1KB/wave each) + 8 labels, all issued first
        float4 v[8]; int lab[8];
        const float* base = y_pred + ((size_t)(p0 << 1) + half) * NCLS + (l32 << 2);
        #pragma unroll
        for (int u = 0; u < 8; ++u) {
            v[u]   = *reinterpret_cast<const float4*>(base + (size_t)(u << 1) * NCLS);
            lab[u] = y_true[((p0 + u) << 1) + half];
        }
        __builtin_amdgcn_sched_barrier(0);   // pin: no compute issued before loads

        // ---- EXP phase: v dies here (S, e0, owner-lane tv fold)
        float S[8], e0[8];
        #pragma unroll
        for (int u = 0; u < 8; ++u) {
            const float ex = __expf(v[u].x), ey = __expf(v[u].y);
            const float ez = __expf(v[u].z), ew = __expf(v[u].w);
            e0[u] = ex;                      // valid on lane 0/32 (col 0) only
            S[u]  = (ex + ey) + (ez + ew);
            if ((lab[u] >> 2) == l32) {      // owner lane folds target logit now
                const int ls = lab[u] & 3;
                ce_local += (ls == 0) ? v[u].x : (ls == 1) ? v[u].y
                          : (ls == 2) ? v[u].z : v[u].w;
            }
        }
        // ---- 8 interleaved 5-step butterflies (S lands on all lanes)
        #pragma unroll
        for (int off = 16; off; off >>= 1) {
            #pragma unroll
            for (int u = 0; u < 8; ++u) S[u] += __shfl_xor(S[u], off);
        }
        // ---- distribute: lane l32==u owns row-pair u of its half
        float e0m = 1.f, Sm = 1.f; int labm = 0;
        #pragma unroll
        for (int u = 0; u < 8; ++u) {
            const float b = __shfl(e0[u], half << 5);   // bcast col-0 exp from lane 0/32
            if (l32 == u) { e0m = b; Sm = S[u]; labm = lab[u]; }
        }
        // ---- wave-parallel epilogue: 16 lanes (8 per half) at once
        if (l32 < 8) {
            const float logS = __logf(Sm);
            ce_local -= logS;
            const float d = (labm == 0) ? e0m : (Sm - e0m);
            const float c0 = __logf(__fmaf_rn(EPS_, Sm, d)) - logS;
            const float contrib = (labm == 0) ? ALPHA * c0 : c0;
            atomicAdd(&sL[labm], contrib);
            atomicAdd(&scnt[labm], 1u);
        }
    }
    // tail: leftover single pairs (empty at 262144 rows; kept for generality)
    for (; p0 < nPairs; ++p0) {
        const int row = (p0 << 1) + half;
        const float4 v = *reinterpret_cast<const float4*>(
            y_pred + (size_t)row * NCLS + (l32 << 2));
        const int lab = y_true[row];
        const float ex = __expf(v.x), ey = __expf(v.y);
        const float ez = __expf(v.z), ew = __expf(v.w);
        float S = (ex + ey) + (ez + ew);
        if ((lab >> 2) == l32) {
            const int ls = lab & 3;
            ce_local += (ls == 0) ? v.x : (ls == 1) ? v.y : (ls == 2) ? v.z : v.w;
        }
        #pragma unroll
        for (int off = 16; off; off >>= 1) S += __shfl_xor(S, off);
        if (l32 == 0) {
            const float logS = __logf(S);
            ce_local -= logS;
            const float d = (lab == 0) ? ex : (S - ex);
            const float c0 = __logf(__fmaf_rn(EPS_, S, d)) - logS;
            const float contrib = (lab == 0) ? ALPHA * c0 : c0;
            atomicAdd(&sL[lab], contrib);
            atomicAdd(&scnt[lab], 1u);
        }
    }
    if ((nrows & 1) && wgl == 0) {
        const int row = nrows - 1;
        const float4 v = *reinterpret_cast<const float4*>(
            y_pred + (size_t)row * NCLS + (l32 << 2));
        const int lab = y_true[row];
        if (half == 0) {
            const float ex = __expf(v.x), ey = __expf(v.y);
            const float ez = __expf(v.z), ew = __expf(v.w);
            float S = (ex + ey) + (ez + ew);
            if ((lab >> 2) == l32) {
                const int ls = lab & 3;
                ce_local += (ls == 0) ? v.x : (ls == 1) ? v.y : (ls == 2) ? v.z : v.w;
            }
            #pragma unroll
            for (int off = 16; off; off >>= 1) S += __shfl_xor(S, off);
            if (l32 == 0) {
                const float logS = __logf(S);
                ce_local -= logS;
                const float d = (lab == 0) ? ex : (S - ex);
                const float c0 = __logf(__fmaf_rn(EPS_, S, d)) - logS;
                const float contrib = (lab == 0) ? ALPHA * c0 : c0;
                atomicAdd(&sL[lab], contrib);
                atomicAdd(&scnt[lab], 1u);
            }
        }
    }

    float lp = ce_local;
    #pragma unroll
    for (int off = 32; off; off >>= 1) lp += __shfl_xor(lp, off);
    if (lane == 0) atomicAdd(&sce, lp);
    __syncthreads();

    // banked flush: 256 blocks / 8 banks -> 32-deep chains on 1024 addresses
    const int bank = blockIdx.x & (NBANK - 1);
    if (t < NCLS) {
        const int c = (t + blockIdx.x) & (NCLS - 1);
        if (scnt[c]) {
            atomicAdd(&gLb[c * NBANK + bank], (double)sL[c]);
            atomicAdd(&gcntb[c * NBANK + bank], scnt[c]);
        }
    }
    if (t == 0) atomicAdd(&gceb[bank], (double)sce);
}

__global__ void loss_final(const double* __restrict__ gLb,
                           const unsigned int* __restrict__ gcntb,
                           const double* __restrict__ gceb,
                           float* __restrict__ out, int nrows)
{
    const int lane = threadIdx.x;   // 64 threads
    double cnt0 = 0.0;
    #pragma unroll
    for (int b = 0; b < NBANK; ++b) cnt0 += (double)gcntb[0 * NBANK + b];
    const double denom = (double)nrows - cnt0;

    double local = 0.0;
    for (int c = lane; c < NCLS; c += 64) {
        double Lc = 0.0, nc = 0.0;
        #pragma unroll
        for (int b = 0; b < NBANK; ++b) {
            Lc += gLb[c * NBANK + b];
            nc += (double)gcntb[c * NBANK + b];
        }
        if (c == 0) local += Lc;                          // ALPHA pre-applied
        else        local += (double)BETA_ * (1.0 - nc / denom) * Lc;
    }
    #pragma unroll
    for (int off = 32; off; off >>= 1) local += __shfl_down(local, off);
    if (lane == 0) {
        double ce = 0.0;
        #pragma unroll
        for (int b = 0; b < NBANK; ++b) ce += gceb[b];
        ce = -ce / (double)nrows;
        out[0] = (float)(ce - local / (double)nrows);
    }
}

extern "C" void kernel_launch(void* const* d_in, const int* in_sizes, int n_in,
                              void* d_out, int out_size, void* d_ws, size_t ws_size,
                              hipStream_t stream) {
    const float* y_pred = (const float*)d_in[0];
    const int*   y_true = (const int*)d_in[1];
    const int nrows = in_sizes[1];

    double*   gLb   = (double*)d_ws;                       // 8192 B
    double*   gceb  = (double*)((char*)d_ws + 8192);       // 64 B
    unsigned* gcntb = (unsigned*)((char*)d_ws + 8256);     // 4096 B

    zero_ws<<<dim3(1), dim3(256), 0, stream>>>((uint32_t*)d_ws);

    loss_main<<<dim3(256), dim3(1024), 0, stream>>>(y_pred, y_true, gLb, gcntb, gceb, nrows);
    loss_final<<<dim3(1), dim3(64), 0, stream>>>(gLb, gcntb, gceb, (float*)d_out, nrows);
}